// Round 2
// baseline (11560.267 us; speedup 1.0000x reference)
//
#include <hip/hip_runtime.h>
#include <hip/hip_cooperative_groups.h>
#include <stdint.h>

namespace cg = cooperative_groups;

#define TSTEPS 101
#define CL 8
#define NCHUNK 13                 /* ceil(101/8) */
#define ROWS 1600
#define NZ1 40
#define NZ2 50
#define OFF2 (NZ1*ROWS)           /* 64000  */
#define OFF3 (OFF2 + NZ2*ROWS)    /* 144000 */
#define NZTOT (OFF3 + NZ2*ROWS)   /* 224000 */
#define BPG 16                    /* batches per block */

__device__ __forceinline__ float sigmoidf_(float v){ return 1.0f/(1.0f+expf(-v)); }

// ---------------------------------------------------------------------------
// Prep: fixed-length CSR (ascending col order), SoA [j][1600] for coalescing.
// For layer 1 also record nx[r] = #nz with col<120 (x-part comes first since
// ascending). Pad cols: L1 pad col=120 (maps to rec index 0, w=0), else 0.
// ---------------------------------------------------------------------------
__global__ void prep_kernel(const float* __restrict__ W1, const float* __restrict__ W2,
                            const float* __restrict__ W3,
                            float* __restrict__ vals, uint16_t* __restrict__ cols,
                            uint8_t* __restrict__ nxArr) {
  int gid = blockIdx.x * blockDim.x + threadIdx.x;
  if (gid >= 3 * ROWS) return;
  int l = gid / ROWS, r = gid - l * ROWS;
  const float* W; int in_f, knz, off;
  if (l == 0)      { W = W1; in_f = 320; knz = NZ1; off = 0;    }
  else if (l == 1) { W = W2; in_f = 400; knz = NZ2; off = OFF2; }
  else             { W = W3; in_f = 400; knz = NZ2; off = OFF3; }
  float* v = vals + off;
  uint16_t* c = cols + off;
  int cnt = 0, cntx = 0;
  for (int col = 0; col < in_f; ++col) {
    float w = W[(size_t)r * in_f + col];
    if (w != 0.0f) {
      if (cnt < knz) { v[cnt * ROWS + r] = w; c[cnt * ROWS + r] = (uint16_t)col; }
      ++cnt;
      if (col < 120) ++cntx;
    }
  }
  for (; cnt < knz; ++cnt) {
    v[cnt * ROWS + r] = 0.0f;
    c[cnt * ROWS + r] = (uint16_t)(l == 0 ? 120 : 0);
  }
  if (l == 0) nxArr[r] = (uint8_t)cntx;
}

// ---------------------------------------------------------------------------
__device__ __forceinline__ void acc4(float* a_, float w, uint32_t q) {
  a_[0] = fmaf(w, (float)(q & 0xffu),        a_[0]);
  a_[1] = fmaf(w, (float)((q >> 8) & 0xffu), a_[1]);
  a_[2] = fmaf(w, (float)((q >> 16) & 0xffu),a_[2]);
  a_[3] = fmaf(w, (float)(q >> 24),          a_[3]);
}

__device__ __forceinline__ uint32_t spread4(uint32_t b4) {
  // low 4 bits -> 4 bytes (0/1)
  return (b4 & 1u) | ((b4 & 2u) << 7) | ((b4 & 4u) << 14) | ((b4 & 8u) << 21);
}

// One row's gather + state update. Keeps bitwise-identical math to the
// verified round-1 kernel (fmaf forms, butterfly order, ascending cols).
template<bool ISL1>
__device__ __forceinline__ void slot_compute(
    int s, int r, int knz, const uint8_t* __restrict__ nxArr,
    const float* __restrict__ vp, const uint16_t* __restrict__ cp,
    const uint8_t (*kS)[40], const float (*kX)[18],
    float (&d)[4][16], float (&mem)[4][16],
    const float* beta, const float* obeta, const float* bias,
    const float* alpha, const float* oalpha, uint32_t (&spkb)[4])
{
  float a_[16];
#pragma unroll
  for (int b = 0; b < 16; ++b) a_[b] = bias[s];
  const float* vpr = vp + r;
  const uint16_t* cpr = cp + r;
  int j = 0;
  if constexpr (ISL1) {
    const int nxr = nxArr[r];
    for (; j < nxr; ++j) {                       // x part (f32 gather)
      const float w = vpr[(size_t)j * ROWS];
      const int cc = cpr[(size_t)j * ROWS];
      const float* xp = &kX[cc][0];
#pragma unroll
      for (int p = 0; p < 8; ++p) {
        float2 xv = *(const float2*)(xp + 2 * p);
        a_[2*p]   = fmaf(w, xv.x, a_[2*p]);
        a_[2*p+1] = fmaf(w, xv.y, a_[2*p+1]);
      }
    }
    for (; j < knz; ++j) {                       // recurrent spike part (u8)
      const float w = vpr[(size_t)j * ROWS];
      const int cc = (int)cpr[(size_t)j * ROWS] - 120;
      const uint8_t* kp = &kS[0][0] + cc * 40;
      const uint2 q0 = *(const uint2*)kp;
      const uint2 q1 = *(const uint2*)(kp + 8);
      acc4(a_ + 0,  w, q0.x); acc4(a_ + 4,  w, q0.y);
      acc4(a_ + 8,  w, q1.x); acc4(a_ + 12, w, q1.y);
    }
  } else {
#pragma unroll 5
    for (j = 0; j < knz; ++j) {
      const float w = vpr[(size_t)j * ROWS];
      const int cc = cpr[(size_t)j * ROWS];
      const uint8_t* kp = &kS[0][0] + cc * 40;
      const uint2 q0 = *(const uint2*)kp;
      const uint2 q1 = *(const uint2*)(kp + 8);
      acc4(a_ + 0,  w, q0.x); acc4(a_ + 4,  w, q0.y);
      acc4(a_ + 8,  w, q1.x); acc4(a_ + 12, w, q1.y);
    }
  }
  uint32_t bits = 0u;
#pragma unroll
  for (int b = 0; b < 16; ++b) {
    float dn = fmaf(beta[s], d[s][b], obeta[s] * a_[b]);
    d[s][b] = dn;
    float v = dn;
    v += __shfl_xor(v, 1);
    v += __shfl_xor(v, 2);
    v += __shfl_xor(v, 4);
    float mo = mem[s][b];
    float so = (mo > 1.0f) ? 1.0f : 0.0f;
    float mn = fmaf(mo - so, alpha[s], oalpha[s] * v);
    mem[s][b] = mn;
    if (mn > 1.0f) bits |= (1u << b);
  }
  spkb[s] = bits;
}

// ---------------------------------------------------------------------------
// Persistent cooperative pipeline kernel.
// Groups of 64 blocks: grp0=L1, grp1=L2, grp2=L3, grp3=readout.
// Each block: one layer x 16 batches, all 1600 rows across 512 threads
// (slots r = tid, tid+512, tid+1024; slot3 r=1536+tid for tid<64).
// Time chunked by CL=8; group lag = grp; one grid.sync per super-step.
// ---------------------------------------------------------------------------
__global__ void __launch_bounds__(512, 1)
snn_pipe(const float* __restrict__ x,
         const float* __restrict__ b1, const float* __restrict__ tm1, const float* __restrict__ tn1,
         const float* __restrict__ b2, const float* __restrict__ tm2, const float* __restrict__ tn2,
         const float* __restrict__ b3, const float* __restrict__ tm3, const float* __restrict__ tn3,
         const float* __restrict__ W4, const float* __restrict__ b4, const float* __restrict__ tm4,
         const float* __restrict__ vals, const uint16_t* __restrict__ cols,
         const uint8_t* __restrict__ nxArr,
         uint8_t* __restrict__ ring,      // [3][2][CL][200][1024] u8 spikes
         float* __restrict__ out)
{
  cg::grid_group grid = cg::this_grid();
  __shared__ __align__(16) uint8_t kS[400][40];  // spikes u8 (stride 40 = bank spread)
  __shared__ __align__(16) float   kX[120][18];  // x f32 (stride 18 = bank spread)
  __shared__ float w4s[12][200];
  __shared__ float sm[16][12];

  const int tid = threadIdx.x;
  const int blk = blockIdx.x;
  const int grp = blk >> 6;          // 0..3
  const int b0  = (blk & 63) * BPG;  // batch base

  for (int i = tid; i < 4000; i += 512) ((uint32_t*)kS)[i] = 0u;

  // ---- compute-group setup ----
  float d[4][16], mem[4][16];
  uint32_t spkb[4];
  float beta[4], obeta[4], bias[4], alpha[4], oalpha[4];
  int strOff = 0, knz = NZ2;
  if (grp < 3) {
    const float *bb, *tnn, *tmm;
    if (grp == 0)      { strOff = 0;    knz = NZ1; bb = b1; tnn = tn1; tmm = tm1; }
    else if (grp == 1) { strOff = OFF2; knz = NZ2; bb = b2; tnn = tn2; tmm = tm2; }
    else               { strOff = OFF3; knz = NZ2; bb = b3; tnn = tn3; tmm = tm3; }
#pragma unroll
    for (int s = 0; s < 4; ++s) {
      const int r = (s < 3) ? (tid + 512 * s) : (1536 + (tid & 63));
      const float bt = sigmoidf_(tnn[r]);
      beta[s] = bt; obeta[s] = 1.0f - bt;
      bias[s] = bb[r];
      const float al = sigmoidf_(tmm[r >> 3]);
      alpha[s] = al; oalpha[s] = 1.0f - al;
#pragma unroll
      for (int b = 0; b < 16; ++b) { d[s][b] = 0.0f; mem[s][b] = 0.0f; }
    }
  }

  // ---- readout-group setup ----
  float m4 = 0.0f, m4acc = 0.0f, a4 = 0.0f, oa4 = 0.0f, b4r = 0.0f;
  if (grp == 3) {
    for (int i = tid; i < 2400; i += 512) w4s[i / 200][i % 200] = W4[i];
    if (tid < 192) {
      const int o = tid >> 4;
      a4 = sigmoidf_(tm4[o]); oa4 = 1.0f - a4; b4r = b4[o];
    }
  }
  __syncthreads();

  const float* vpB = vals + strOff;
  const uint16_t* cpB = cols + strOff;

  for (int u = 0; u < NCHUNK + 3; ++u) {
    const int c = u - grp;
    if (c >= 0 && c < NCHUNK) {
      const int t0 = c * CL;
      const int t1 = (t0 + CL < TSTEPS) ? (t0 + CL) : TSTEPS;
      for (int t = t0; t < t1; ++t) {
        // ---------- phase A: stage ----------
        if (grp == 0) {
          for (int idx = tid; idx < 1920; idx += 512) {
            const int b = idx / 120, cc = idx - b * 120;
            const int ch = cc / 40, f = cc - ch * 40;
            kX[cc][b] = x[(((size_t)(b0 + b) * 3 + ch) * TSTEPS + t) * 40 + f];
          }
        } else {
          const int srcL = (grp == 3) ? 2 : (grp - 1);
          const uint8_t* rp = ring +
              ((((size_t)(srcL * 2 + (c & 1)) * CL) + (t - t0)) * 200) * 1024;
          if (tid < 200) {
            const uint4 v = *(const uint4*)(rp + (size_t)tid * 1024 + b0);
            *(uint2*)&kS[tid][0] = make_uint2(v.x, v.y);
            *(uint2*)&kS[tid][8] = make_uint2(v.z, v.w);
          }
        }
        __syncthreads();
        // ---------- phase B: gather + state update (regs) ----------
        if (grp < 3) {
          if (grp == 0) {
            slot_compute<true >(0, tid,        knz, nxArr, vpB, cpB, kS, kX, d, mem, beta, obeta, bias, alpha, oalpha, spkb);
            slot_compute<true >(1, tid + 512,  knz, nxArr, vpB, cpB, kS, kX, d, mem, beta, obeta, bias, alpha, oalpha, spkb);
            slot_compute<true >(2, tid + 1024, knz, nxArr, vpB, cpB, kS, kX, d, mem, beta, obeta, bias, alpha, oalpha, spkb);
            if (tid < 64)
              slot_compute<true >(3, 1536 + tid, knz, nxArr, vpB, cpB, kS, kX, d, mem, beta, obeta, bias, alpha, oalpha, spkb);
          } else {
            slot_compute<false>(0, tid,        knz, nxArr, vpB, cpB, kS, kX, d, mem, beta, obeta, bias, alpha, oalpha, spkb);
            slot_compute<false>(1, tid + 512,  knz, nxArr, vpB, cpB, kS, kX, d, mem, beta, obeta, bias, alpha, oalpha, spkb);
            slot_compute<false>(2, tid + 1024, knz, nxArr, vpB, cpB, kS, kX, d, mem, beta, obeta, bias, alpha, oalpha, spkb);
            if (tid < 64)
              slot_compute<false>(3, 1536 + tid, knz, nxArr, vpB, cpB, kS, kX, d, mem, beta, obeta, bias, alpha, oalpha, spkb);
          }
        } else if (tid < 192) {
          const int o = tid >> 4, b = tid & 15;
          float dot = b4r;
#pragma unroll 8
          for (int n = 0; n < 200; ++n)
            dot = fmaf(w4s[o][n], (float)kS[n][b], dot);
          m4 = a4 * m4 + oa4 * dot;
          m4acc += m4;
        }
        __syncthreads();
        // ---------- phase C: publish spikes (LDS rec + global ring) ----------
        if (grp < 3) {
          uint8_t* wp = ring +
              ((((size_t)(grp * 2 + (c & 1)) * CL) + (t - t0)) * 200) * 1024;
#pragma unroll
          for (int s = 0; s < 4; ++s) {
            if (s == 3 && tid >= 64) break;
            if ((tid & 7) == 0) {
              const int r = (s < 3) ? (tid + 512 * s) : (1536 + tid);
              const int n = r >> 3;
              const uint32_t bits = spkb[s];
              const uint32_t w0 = spread4(bits);
              const uint32_t w1 = spread4(bits >> 4);
              const uint32_t w2 = spread4(bits >> 8);
              const uint32_t w3 = spread4(bits >> 12);
              uint8_t* kp = (grp == 0) ? &kS[n][0] : &kS[200 + n][0];
              *(uint2*)kp       = make_uint2(w0, w1);
              *(uint2*)(kp + 8) = make_uint2(w2, w3);
              *(uint4*)(wp + (size_t)n * 1024 + b0) = make_uint4(w0, w1, w2, w3);
            }
          }
        }
      }
    }
    __threadfence();
    grid.sync();
  }

  // ---------- epilogue: log_softmax (readout group) ----------
  if (grp == 3) {
    if (tid < 192) sm[tid & 15][tid >> 4] = m4acc * (1.0f / (float)TSTEPS);
    __syncthreads();
    if (tid < 16) {
      float v[12], mx = -1e30f;
#pragma unroll
      for (int o = 0; o < 12; ++o) { v[o] = sm[tid][o]; mx = fmaxf(mx, v[o]); }
      float ssum = 0.0f;
#pragma unroll
      for (int o = 0; o < 12; ++o) ssum += expf(v[o] - mx);
      const float ls = logf(ssum);
#pragma unroll
      for (int o = 0; o < 12; ++o)
        out[(size_t)(b0 + tid) * 12 + o] = v[o] - mx - ls;
    }
  }
}

// ---------------------------------------------------------------------------
extern "C" void kernel_launch(void* const* d_in, const int* in_sizes, int n_in,
                              void* d_out, int out_size, void* d_ws, size_t ws_size,
                              hipStream_t stream) {
  (void)in_sizes; (void)n_in; (void)out_size; (void)ws_size;
  const float* x   = (const float*)d_in[0];
  const float* W1  = (const float*)d_in[1];
  const float* b1  = (const float*)d_in[2];
  const float* tm1 = (const float*)d_in[3];
  const float* tn1 = (const float*)d_in[4];
  const float* W2  = (const float*)d_in[5];
  const float* b2  = (const float*)d_in[6];
  const float* tm2 = (const float*)d_in[7];
  const float* tn2 = (const float*)d_in[8];
  const float* W3  = (const float*)d_in[9];
  const float* b3  = (const float*)d_in[10];
  const float* tm3 = (const float*)d_in[11];
  const float* tn3 = (const float*)d_in[12];
  const float* W4  = (const float*)d_in[13];
  const float* b4  = (const float*)d_in[14];
  const float* tm4 = (const float*)d_in[15];

  float*    vals = (float*)d_ws;
  uint16_t* cols = (uint16_t*)((char*)d_ws + (size_t)NZTOT * 4);
  uint8_t*  nx   = (uint8_t*)((char*)d_ws + (size_t)NZTOT * 6);
  size_t ringOff = (((size_t)NZTOT * 6 + ROWS) + 1023) & ~(size_t)1023;
  uint8_t*  ring = (uint8_t*)((char*)d_ws + ringOff);   // 3*2*8*200*1024 = 9.8 MB
  float*    outp = (float*)d_out;

  prep_kernel<<<dim3(19), dim3(256), 0, stream>>>(W1, W2, W3, vals, cols, nx);

  void* args[] = { (void*)&x,
                   (void*)&b1, (void*)&tm1, (void*)&tn1,
                   (void*)&b2, (void*)&tm2, (void*)&tn2,
                   (void*)&b3, (void*)&tm3, (void*)&tn3,
                   (void*)&W4, (void*)&b4, (void*)&tm4,
                   (void*)&vals, (void*)&cols, (void*)&nx,
                   (void*)&ring, (void*)&outp };
  hipLaunchCooperativeKernel((const void*)snn_pipe, dim3(256), dim3(512),
                             args, 0, stream);
}

// Round 3
// 10263.657 us; speedup vs baseline: 1.1263x; 1.1263x over previous
//
#include <hip/hip_runtime.h>
#include <hip/hip_cooperative_groups.h>
#include <stdint.h>

namespace cg = cooperative_groups;

#define T_STEPS 101
#define ROWS 1600
#define NTHR 512
#define NZ1 40
#define NZ2 50
#define OFF2 (NZ1 * ROWS)              /* 64000  */
#define OFF3 (OFF2 + NZ2 * ROWS)       /* 144000 */
#define NZTOT (OFF3 + NZ2 * ROWS)      /* 224000 */

__device__ __forceinline__ float sigmoidf(float v) { return 1.0f / (1.0f + expf(-v)); }

// ---------------------------------------------------------------------------
// Prep: extract fixed-length CSR (exactly 40/50 nonzeros per row by mask
// construction) from the masked dense weights. SoA layout vals[j*1600 + r]
// so the main kernel's weight stream is lane-coalesced.
// ---------------------------------------------------------------------------
__global__ void prep_kernel(const float* __restrict__ W1, const float* __restrict__ W2,
                            const float* __restrict__ W3,
                            float* __restrict__ vals, uint16_t* __restrict__ cols) {
  int gid = blockIdx.x * blockDim.x + threadIdx.x;
  if (gid >= 3 * ROWS) return;
  int l = gid / ROWS, r = gid - l * ROWS;
  const float* W; int in_f, knz, off;
  if (l == 0)      { W = W1; in_f = 320; knz = NZ1; off = 0;    }
  else if (l == 1) { W = W2; in_f = 400; knz = NZ2; off = OFF2; }
  else             { W = W3; in_f = 400; knz = NZ2; off = OFF3; }
  float* v = vals + off;
  uint16_t* c = cols + off;
  int cnt = 0;
  for (int col = 0; col < in_f; ++col) {
    float w = W[(size_t)r * in_f + col];
    if (w != 0.0f) {
      if (cnt < knz) { v[cnt * ROWS + r] = w; c[cnt * ROWS + r] = (uint16_t)col; }
      ++cnt;
    }
  }
  for (; cnt < knz; ++cnt) { v[cnt * ROWS + r] = 0.0f; c[cnt * ROWS + r] = 0; }
}

// ---------------------------------------------------------------------------
// One layer's step for this thread's row slots.
// Rows: slot i<3 -> r = tid + 512*i ; slot 3 -> r = 1536 + tid (wave 0 only).
// Lane groups of 8 (8-aligned tids) own one neuron's 8 branches.
// ---------------------------------------------------------------------------
template<int L, int KNZ, bool U8>
__device__ __forceinline__ void layer_step(
    int tid,
    const float* __restrict__ vals, const uint16_t* __restrict__ cols,
    float (&d)[3][4][4],
    const float (&beta)[3][4], const float (&bia)[3][4], const float (&alpha)[3][4],
    const float (*k1f)[4], const uint8_t (*k23)[4],
    uint8_t (*s_l)[4], float (*mem_l)[4])
{
#pragma unroll
  for (int i = 0; i < 4; ++i) {
    if (i == 3 && tid >= 64) break;          // wave-uniform: only wave 0 has slot 3
    const int r = (i < 3) ? (tid + NTHR * i) : (1536 + tid);
    float a0 = bia[L][i], a1 = a0, a2 = a0, a3 = a0;
    const float* vp = vals + r;
    const uint16_t* cp = cols + r;
#pragma unroll 10
    for (int j = 0; j < KNZ; ++j) {
      const float w = vp[(size_t)j * ROWS];
      const int c = cp[(size_t)j * ROWS];
      if constexpr (U8) {
        const uint32_t s4 = *reinterpret_cast<const uint32_t*>(k23[c]);
        a0 = fmaf(w, (float)(s4 & 0xffu), a0);
        a1 = fmaf(w, (float)((s4 >> 8) & 0xffu), a1);
        a2 = fmaf(w, (float)((s4 >> 16) & 0xffu), a2);
        a3 = fmaf(w, (float)(s4 >> 24), a3);
      } else {
        const float4 kv = *reinterpret_cast<const float4*>(k1f[c]);
        a0 = fmaf(w, kv.x, a0);
        a1 = fmaf(w, kv.y, a1);
        a2 = fmaf(w, kv.z, a2);
        a3 = fmaf(w, kv.w, a3);
      }
    }
    // d = beta*d + (1-beta)*ff
    const float bt = beta[L][i], ob = 1.0f - bt;
    float d0 = fmaf(bt, d[L][i][0], ob * a0);
    float d1 = fmaf(bt, d[L][i][1], ob * a1);
    float d2 = fmaf(bt, d[L][i][2], ob * a2);
    float d3 = fmaf(bt, d[L][i][3], ob * a3);
    d[L][i][0] = d0; d[L][i][1] = d1; d[L][i][2] = d2; d[L][i][3] = d3;
    // branch sum over the neuron's 8 rows (8 consecutive, 8-aligned lanes)
    d0 += __shfl_xor(d0, 1); d0 += __shfl_xor(d0, 2); d0 += __shfl_xor(d0, 4);
    d1 += __shfl_xor(d1, 1); d1 += __shfl_xor(d1, 2); d1 += __shfl_xor(d1, 4);
    d2 += __shfl_xor(d2, 1); d2 += __shfl_xor(d2, 2); d2 += __shfl_xor(d2, 4);
    d3 += __shfl_xor(d3, 1); d3 += __shfl_xor(d3, 2); d3 += __shfl_xor(d3, 4);
    if ((tid & 7) == 0) {
      const int n = r >> 3;
      const float al = alpha[L][i], oa = 1.0f - al;
      float4 mv = *reinterpret_cast<float4*>(&mem_l[n][0]);
      const uint32_t so = *reinterpret_cast<uint32_t*>(&s_l[n][0]);
      // mem = (mem - vth*spike)*alpha + (1-alpha)*sum(d)
      const float m0 = fmaf(mv.x - (float)(so & 0xffu),         al, oa * d0);
      const float m1 = fmaf(mv.y - (float)((so >> 8) & 0xffu),  al, oa * d1);
      const float m2 = fmaf(mv.z - (float)((so >> 16) & 0xffu), al, oa * d2);
      const float m3 = fmaf(mv.w - (float)(so >> 24),           al, oa * d3);
      *reinterpret_cast<float4*>(&mem_l[n][0]) = make_float4(m0, m1, m2, m3);
      const uint32_t sn = (m0 > 1.0f ? 1u : 0u)
                        | (m1 > 1.0f ? 0x100u : 0u)
                        | (m2 > 1.0f ? 0x10000u : 0u)
                        | (m3 > 1.0f ? 0x1000000u : 0u);
      *reinterpret_cast<uint32_t*>(&s_l[n][0]) = sn;
    }
  }
}

// ---------------------------------------------------------------------------
// Persistent main kernel: 256 blocks x 512 threads, 4 batch elements / block.
// Cooperative: one grid.sync() per timestep keeps all blocks (and hence the
// 32 blocks sharing each XCD's L2) in lockstep, so the 1.34 MB CSR weight
// stream stays L2-resident instead of being re-fetched from L3/HBM.
// ---------------------------------------------------------------------------
__global__ void __launch_bounds__(NTHR, 2)
snn_main(const float* __restrict__ x,
         const float* __restrict__ b1, const float* __restrict__ tm1, const float* __restrict__ tn1,
         const float* __restrict__ b2, const float* __restrict__ tm2, const float* __restrict__ tn2,
         const float* __restrict__ b3, const float* __restrict__ tm3, const float* __restrict__ tn3,
         const float* __restrict__ W4, const float* __restrict__ b4, const float* __restrict__ tm4,
         const float* __restrict__ vals, const uint16_t* __restrict__ cols,
         float* __restrict__ out)
{
  cg::grid_group grid = cg::this_grid();
  __shared__ __align__(16) float   k1f[320][4];       // layer-1 input (x real-valued + s1)
  __shared__ __align__(4)  uint8_t k23[400][4];       // layer-2/3 input (binary spikes)
  __shared__ __align__(4)  uint8_t s_lds[3][200][4];  // spike state (exact 0/1)
  __shared__ __align__(16) float   mem_lds[3][200][4];
  __shared__ float w4_lds[12][201];                   // padded: stride 201 breaks bank stride

  const int tid = threadIdx.x;
  const int bg  = blockIdx.x;          // batch group: batches bg*4 .. bg*4+3

  // zero states
  for (int idx = tid; idx < 3 * 200; idx += NTHR) {
    reinterpret_cast<uint32_t*>(&s_lds[0][0][0])[idx] = 0u;
    float4* mp = reinterpret_cast<float4*>(&mem_lds[0][0][0]);
    mp[idx] = make_float4(0.f, 0.f, 0.f, 0.f);
  }
  for (int idx = tid; idx < 12 * 200; idx += NTHR)
    w4_lds[idx / 200][idx % 200] = W4[idx];

  float d[3][4][4];
#pragma unroll
  for (int l = 0; l < 3; ++l)
#pragma unroll
    for (int i = 0; i < 4; ++i)
#pragma unroll
      for (int b = 0; b < 4; ++b) d[l][i][b] = 0.0f;

  float beta[3][4], bia[3][4], alpha[3][4];
#pragma unroll
  for (int i = 0; i < 4; ++i) {
    const int r = (i < 3) ? (tid + NTHR * i) : (1536 + (tid & 63));
    const int n = r >> 3;
    beta[0][i] = sigmoidf(tn1[r]); bia[0][i] = b1[r]; alpha[0][i] = sigmoidf(tm1[n]);
    beta[1][i] = sigmoidf(tn2[r]); bia[1][i] = b2[r]; alpha[1][i] = sigmoidf(tm2[n]);
    beta[2][i] = sigmoidf(tn3[r]); bia[2][i] = b3[r]; alpha[2][i] = sigmoidf(tm3[n]);
  }

  float m4_reg = 0.0f, m4_acc = 0.0f, a4 = 0.0f, b4r = 0.0f;
  if (tid < 48) { const int o = tid >> 2; a4 = sigmoidf(tm4[o]); b4r = b4[o]; }
  __syncthreads();

  for (int t = 0; t < T_STEPS; ++t) {
    // ---- build k1 = [x_t | s1(old)] -----------------------------------
    if (tid < 480) {
      const int bat = tid / 120, cf = tid - bat * 120;
      const int c = cf / 40, f = cf - c * 40;
      const int b = bg * 4 + bat;
      k1f[cf][bat] = x[(((size_t)b * 3 + c) * T_STEPS + t) * 40 + f];
    }
    if (tid < 200) {
      const uint32_t so = reinterpret_cast<const uint32_t*>(&s_lds[0][0][0])[tid];
      *reinterpret_cast<float4*>(&k1f[120 + tid][0]) =
          make_float4((float)(so & 0xffu), (float)((so >> 8) & 0xffu),
                      (float)((so >> 16) & 0xffu), (float)(so >> 24));
    }
    __syncthreads();
    layer_step<0, NZ1, false>(tid, vals, cols, d, beta, bia, alpha,
                              k1f, k23, s_lds[0], mem_lds[0]);
    __syncthreads();
    // ---- build k2 = [s1(new) | s2(old)] -------------------------------
    if (tid < 200)
      reinterpret_cast<uint32_t*>(&k23[0][0])[tid] =
          reinterpret_cast<const uint32_t*>(&s_lds[0][0][0])[tid];
    else if (tid < 400)
      reinterpret_cast<uint32_t*>(&k23[0][0])[tid] =
          reinterpret_cast<const uint32_t*>(&s_lds[1][0][0])[tid - 200];
    __syncthreads();
    layer_step<1, NZ2, true>(tid, vals + OFF2, cols + OFF2, d, beta, bia, alpha,
                             k1f, k23, s_lds[1], mem_lds[1]);
    __syncthreads();
    // ---- build k3 = [s2(new) | s3(old)] -------------------------------
    if (tid < 200)
      reinterpret_cast<uint32_t*>(&k23[0][0])[tid] =
          reinterpret_cast<const uint32_t*>(&s_lds[1][0][0])[tid];
    else if (tid < 400)
      reinterpret_cast<uint32_t*>(&k23[0][0])[tid] =
          reinterpret_cast<const uint32_t*>(&s_lds[2][0][0])[tid - 200];
    __syncthreads();
    layer_step<2, NZ2, true>(tid, vals + OFF3, cols + OFF3, d, beta, bia, alpha,
                             k1f, k23, s_lds[2], mem_lds[2]);
    __syncthreads();
    // ---- leaky readout ------------------------------------------------
    if (tid < 48) {
      const int o = tid >> 2, bat = tid & 3;
      float dot = b4r;
#pragma unroll 8
      for (int n = 0; n < 200; ++n)
        dot = fmaf(w4_lds[o][n], (float)s_lds[2][n][bat], dot);
      m4_reg = a4 * m4_reg + (1.0f - a4) * dot;
      m4_acc += m4_reg;
    }
    // pacing barrier: keep all blocks lockstep so the shared weight stream
    // stays resident in each XCD's L2 (no data exchanged -> no fence needed)
    grid.sync();
  }

  // ---- log_softmax(acc / T) -------------------------------------------
  if (tid < 48) {
    const int o = tid >> 2, bat = tid & 3;
    k1f[o][bat] = m4_acc * (1.0f / (float)T_STEPS);
  }
  __syncthreads();
  if (tid < 4) {
    const int bat = tid;
    float v[12], mx = -1e30f;
#pragma unroll
    for (int o = 0; o < 12; ++o) { v[o] = k1f[o][bat]; mx = fmaxf(mx, v[o]); }
    float s = 0.0f;
#pragma unroll
    for (int o = 0; o < 12; ++o) s += expf(v[o] - mx);
    const float ls = logf(s);
#pragma unroll
    for (int o = 0; o < 12; ++o)
      out[((size_t)(bg * 4 + bat)) * 12 + o] = v[o] - mx - ls;
  }
}

// ---------------------------------------------------------------------------
extern "C" void kernel_launch(void* const* d_in, const int* in_sizes, int n_in,
                              void* d_out, int out_size, void* d_ws, size_t ws_size,
                              hipStream_t stream) {
  (void)in_sizes; (void)n_in; (void)out_size; (void)ws_size;
  const float* x   = (const float*)d_in[0];
  const float* W1  = (const float*)d_in[1];
  const float* b1  = (const float*)d_in[2];
  const float* tm1 = (const float*)d_in[3];
  const float* tn1 = (const float*)d_in[4];
  const float* W2  = (const float*)d_in[5];
  const float* b2  = (const float*)d_in[6];
  const float* tm2 = (const float*)d_in[7];
  const float* tn2 = (const float*)d_in[8];
  const float* W3  = (const float*)d_in[9];
  const float* b3  = (const float*)d_in[10];
  const float* tm3 = (const float*)d_in[11];
  const float* tn3 = (const float*)d_in[12];
  const float* W4  = (const float*)d_in[13];
  const float* b4  = (const float*)d_in[14];
  const float* tm4 = (const float*)d_in[15];

  float*    vals = (float*)d_ws;                                     // 224000 floats
  uint16_t* cols = (uint16_t*)((char*)d_ws + (size_t)NZTOT * 4);     // 224000 u16
  float*    outp = (float*)d_out;

  prep_kernel<<<dim3(19), dim3(256), 0, stream>>>(W1, W2, W3, vals, cols);

  void* args[] = { (void*)&x,
                   (void*)&b1, (void*)&tm1, (void*)&tn1,
                   (void*)&b2, (void*)&tm2, (void*)&tn2,
                   (void*)&b3, (void*)&tm3, (void*)&tn3,
                   (void*)&W4, (void*)&b4, (void*)&tm4,
                   (void*)&vals, (void*)&cols, (void*)&outp };
  hipLaunchCooperativeKernel((const void*)snn_main, dim3(256), dim3(NTHR),
                             args, 0, stream);
}